// Round 1
// baseline (48.921 us; speedup 1.0000x reference)
//
#include <hip/hip_runtime.h>

typedef unsigned long long u64;

#define BB 8
#define CC 32
#define NN 512
#define TT 12
#define NBLK (BB*CC)   // 256 blocks, one per (b, channel)

__device__ __forceinline__ float eluf(float x) {
  return x > 0.0f ? x : (expf(x) - 1.0f);
}
__device__ __forceinline__ float sigmf(float x) {
  if (x >= 0.0f) return 1.0f / (1.0f + expf(-x));
  float e = expf(x);
  return e / (1.0f + e);
}

// Tagged 8-byte slot: hi32 = tag, lo32 = float payload. Payload travels with
// the tag in one atomic -> relaxed agent-scope atomics suffice, no fences.
__device__ __forceinline__ u64 pack_slot(unsigned tag, float v) {
  return ((u64)tag << 32) | (u64)__float_as_uint(v);
}

__global__ __launch_bounds__(256, 1)
void glstm_fused(const float* __restrict__ xg,     // (B,C,N,T)
                 const float* __restrict__ cellg,  // (B,C,N)
                 const float* __restrict__ w1g,    // (T,8,C,C)
                 const float* __restrict__ w2g,    // (T,8,C,C)
                 const float* __restrict__ biasg,  // (4,C,N,T)
                 float* __restrict__ outg,         // (B,C,N,T) ++ (B,C,N)
                 u64* slots)
{
  // 96KB bias tile -> 1 block/CU -> all 256 blocks co-resident (spin-safe)
  __shared__ float biasL[4][TT][NN];
  __shared__ float preS[4];
  __shared__ float redS[4];
  __shared__ float wpart[13][4];

  const int blk  = blockIdx.x;
  const int b    = blk >> 5;
  const int tid  = threadIdx.x;
  const int lane = tid & 63;
  const int wv   = tid >> 6;
  const int ch   = blk & 31;

  u64* csum_slot = slots;            // [2][NBLK]  double-buffered by parity
  u64* xsum_slot = slots + 2*NBLK;   // [TT][NBLK] write-once, tag=1

  // ---- cell row lives in registers for the whole kernel ----
  float c0 = cellg[blk*NN + 2*tid];
  float c1 = cellg[blk*NN + 2*tid + 1];

  // ---- phase 0: per-t x row-sums + csum(state0) + bias -> LDS ----
  float xs[TT];
  #pragma unroll
  for (int t=0;t<TT;t++) xs[t]=0.0f;
  const float* xrow = xg + blk*NN*TT;
  #pragma unroll
  for (int half=0; half<2; half++){
    int n = tid + half*256;
    const float4* p = (const float4*)(xrow + n*TT);   // 12 consec floats
    float4 v0=p[0], v1=p[1], v2=p[2];
    xs[0]+=v0.x;  xs[1]+=v0.y;  xs[2]+=v0.z;  xs[3]+=v0.w;
    xs[4]+=v1.x;  xs[5]+=v1.y;  xs[6]+=v1.z;  xs[7]+=v1.w;
    xs[8]+=v2.x;  xs[9]+=v2.y;  xs[10]+=v2.z; xs[11]+=v2.w;
  }
  float cpart = c0 + c1;
  #pragma unroll
  for (int off=32; off>=1; off>>=1){
    #pragma unroll
    for (int t=0;t<TT;t++) xs[t] += __shfl_xor(xs[t], off, 64);
    cpart += __shfl_xor(cpart, off, 64);
  }
  if (lane == 0){
    #pragma unroll
    for (int t=0;t<TT;t++) wpart[t][wv] = xs[t];
    wpart[12][wv] = cpart;
  }

  #pragma unroll
  for (int k=0;k<4;k++){
    #pragma unroll
    for (int half=0; half<2; half++){
      int n = tid + half*256;
      const float4* p = (const float4*)(biasg + ((k*CC + ch)*NN + n)*TT);
      float4 v0=p[0], v1=p[1], v2=p[2];
      biasL[k][0][n]=v0.x;  biasL[k][1][n]=v0.y;  biasL[k][2][n]=v0.z;  biasL[k][3][n]=v0.w;
      biasL[k][4][n]=v1.x;  biasL[k][5][n]=v1.y;  biasL[k][6][n]=v1.z;  biasL[k][7][n]=v1.w;
      biasL[k][8][n]=v2.x;  biasL[k][9][n]=v2.y;  biasL[k][10][n]=v2.z; biasL[k][11][n]=v2.w;
    }
  }
  __syncthreads();

  if (tid < 13){
    float v = wpart[tid][0] + wpart[tid][1] + wpart[tid][2] + wpart[tid][3];
    u64 pk = pack_slot(1u, v);   // xsum tag=1; csum state0 tag=0+1=1
    if (tid < TT)
      __hip_atomic_store(&xsum_slot[tid*NBLK + blk], pk,
                         __ATOMIC_RELAXED, __HIP_MEMORY_SCOPE_AGENT);
    else
      __hip_atomic_store(&csum_slot[blk], pk,
                         __ATOMIC_RELAXED, __HIP_MEMORY_SCOPE_AGENT);
  }

  float* outrow = outg + blk*NN*TT;

  // ---- 12 sequential steps ----
  for (int s=0; s<TT; s++){
    // gather zsum: lanes 0-31 -> xsum[s][b][*] (x-heads), lanes 32-63 -> csum (c-heads)
    const int i0 = lane & 31;
    u64* slot = (lane < 32)
      ? &xsum_slot[s*NBLK + b*CC + i0]
      : &csum_slot[(s&1)*NBLK + b*CC + i0];
    const unsigned want = (lane < 32) ? 1u : (unsigned)(s+1);
    u64 v = __hip_atomic_load(slot, __ATOMIC_RELAXED, __HIP_MEMORY_SCOPE_AGENT);
    int guard = 0;
    while ((unsigned)(v >> 32) != want){
      __builtin_amdgcn_s_sleep(1);
      v = __hip_atomic_load(slot, __ATOMIC_RELAXED, __HIP_MEMORY_SCOPE_AGENT);
      if (++guard > 1000000) break;   // never triggers in practice; avoids hangs
    }
    float zs = __uint_as_float((unsigned)v);

    // 8 heads: wave wv handles head wv (lanes<32, x-input) and wv+4 (lanes>=32, c-input)
    const int m = wv + ((lane >> 5) << 2);
    const float* w1m = w1g + (s*8 + m)*CC*CC + i0;
    float s1 = 0.0f;
    #pragma unroll
    for (int j=0;j<CC;j++){
      float a = __shfl(zs, j, 32);           // zsum[j] broadcast within half
      s1 = fmaf(a, w1m[j*CC], s1);           // w1[j][i0]
    }
    float h1 = eluf(eluf(s1));
    float pp = h1 * w2g[((s*8 + m)*CC + i0)*CC + ch];   // w2[i0][ch]
    #pragma unroll
    for (int off=16; off>=1; off>>=1) pp += __shfl_xor(pp, off, 32);
    float ov = eluf(eluf(eluf(512.0f * pp)));           // elu^3(N * h1@w2)
    float prew = ov + __shfl_xor(ov, 32, 64);           // out_m + out_{m+4}
    if (lane == 0) preS[wv] = prew;
    __syncthreads();
    const float g0 = preS[0], g1 = preS[1], g2 = preS[2], g3 = preS[3];

    // elementwise gate update for n = 2*tid, 2*tid+1 (c stays in registers)
    const int n0 = 2*tid;
    float ig0 = sigmf(g0 + biasL[0][s][n0]);
    float fg0 = sigmf(g1 + biasL[1][s][n0]);
    float ct0 = tanhf(g3 + biasL[3][s][n0]);
    float ig1 = sigmf(g0 + biasL[0][s][n0+1]);
    float fg1 = sigmf(g1 + biasL[1][s][n0+1]);
    float ct1 = tanhf(g3 + biasL[3][s][n0+1]);
    c0 = fg0*c0 + ig0*ct0;
    c1 = fg1*c1 + ig1*ct1;
    float csp = c0 + c1;
    __syncthreads();   // preS reads done before next iter's writes

    if (s < TT-1){
      // publish csum(state s+1) ASAP so peer blocks can start step s+1
      #pragma unroll
      for (int off=32; off>=1; off>>=1) csp += __shfl_xor(csp, off, 64);
      if (lane == 0) redS[wv] = csp;
      __syncthreads();
      if (tid == 0){
        float tot = redS[0]+redS[1]+redS[2]+redS[3];
        __hip_atomic_store(&csum_slot[((s+1)&1)*NBLK + blk],
                           pack_slot((unsigned)(s+2), tot),
                           __ATOMIC_RELAXED, __HIP_MEMORY_SCOPE_AGENT);
      }
    }

    // H writes after the publish (stores are fire-and-forget)
    float og0 = sigmf(g2 + biasL[2][s][n0]);
    float og1 = sigmf(g2 + biasL[2][s][n0+1]);
    outrow[n0*TT + s]     = og0 * tanhf(c0);
    outrow[(n0+1)*TT + s] = og1 * tanhf(c1);
  }

  // final cell state
  float* cf = outg + NBLK*NN*TT + blk*NN;
  cf[2*tid]   = c0;
  cf[2*tid+1] = c1;
}

extern "C" void kernel_launch(void* const* d_in, const int* in_sizes, int n_in,
                              void* d_out, int out_size, void* d_ws, size_t ws_size,
                              hipStream_t stream)
{
  (void)in_sizes; (void)n_in; (void)out_size; (void)ws_size;
  // setup_inputs order: input, cell, adj, w1, a1, w2, a2, bias
  const float* xg    = (const float*)d_in[0];
  const float* cellg = (const float*)d_in[1];
  const float* w1g   = (const float*)d_in[3];
  const float* w2g   = (const float*)d_in[5];
  const float* biasg = (const float*)d_in[7];
  float* outg = (float*)d_out;
  u64* slots = (u64*)d_ws;

  // reset sync tags every launch (ws is poisoned once and never re-poisoned)
  hipMemsetAsync(d_ws, 0, (size_t)(2*NBLK + TT*NBLK)*sizeof(u64), stream);
  glstm_fused<<<dim3(NBLK), dim3(256), 0, stream>>>(xg, cellg, w1g, w2g, biasg, outg, slots);
}